// Round 1
// baseline (476.771 us; speedup 1.0000x reference)
//
#include <hip/hip_runtime.h>
#include <hip/hip_bf16.h>

typedef __bf16 bf16x8 __attribute__((ext_vector_type(8)));
typedef float f32x4 __attribute__((ext_vector_type(4)));

// ---------------------------------------------------------------------------
// fp32 -> bf16 elementwise convert (vectorized: float4 in, ushort4 out)
// ---------------------------------------------------------------------------
__global__ __launch_bounds__(256) void cvt_f32_to_bf16_k(const float* __restrict__ in,
                                                         __hip_bfloat16* __restrict__ out,
                                                         int n4) {
    int i = blockIdx.x * blockDim.x + threadIdx.x;
    if (i < n4) {
        float4 v = reinterpret_cast<const float4*>(in)[i];
        __hip_bfloat16 a = __float2bfloat16(v.x);
        __hip_bfloat16 b = __float2bfloat16(v.y);
        __hip_bfloat16 c = __float2bfloat16(v.z);
        __hip_bfloat16 d = __float2bfloat16(v.w);
        ushort4 o;
        o.x = *reinterpret_cast<unsigned short*>(&a);
        o.y = *reinterpret_cast<unsigned short*>(&b);
        o.z = *reinterpret_cast<unsigned short*>(&c);
        o.w = *reinterpret_cast<unsigned short*>(&d);
        reinterpret_cast<ushort4*>(out)[i] = o;
    }
}

// ---------------------------------------------------------------------------
// fp32 [R][Cn] -> bf16 [Cn][R] transposed convert (LDS 32x32 tile)
// ---------------------------------------------------------------------------
__global__ __launch_bounds__(256) void transpose_cvt(const float* __restrict__ in,
                                                     __hip_bfloat16* __restrict__ out,
                                                     int R, int Cn) {
    __shared__ float tile[32][33];
    const int c0 = blockIdx.x * 32, r0 = blockIdx.y * 32;
    const int tx = threadIdx.x & 31, ty = threadIdx.x >> 5;  // 32 x 8
#pragma unroll
    for (int i = 0; i < 4; ++i)
        tile[ty + i * 8][tx] = in[(size_t)(r0 + ty + i * 8) * Cn + c0 + tx];
    __syncthreads();
#pragma unroll
    for (int i = 0; i < 4; ++i)
        out[(size_t)(c0 + ty + i * 8) * R + r0 + tx] = __float2bfloat16(tile[tx][ty + i * 8]);
}

// ---------------------------------------------------------------------------
// bf16 GEMM, C = A[M][K] * B, with B given transposed: Bt[N][K].
// m97 structure: 128x128 tile, BK=32, 4 waves each owning 64x64 (4x4 frags of
// 16x16x32 MFMA), global_load_lds width-16 staging, 2 barriers per K-step.
// Output fp32 or bf16.
// ---------------------------------------------------------------------------
template <bool OUT_BF16>
__global__ __launch_bounds__(256) void gemm_bt(const __hip_bfloat16* __restrict__ A,
                                               const __hip_bfloat16* __restrict__ Bt,
                                               __hip_bfloat16* __restrict__ Cb,
                                               float* __restrict__ Cf,
                                               int M, int N, int K) {
    __shared__ __attribute__((aligned(16))) __hip_bfloat16 As[128 * 32];
    __shared__ __attribute__((aligned(16))) __hip_bfloat16 Bs[128 * 32];
    const int tid = threadIdx.x;
    const int lane = tid & 63, wid = tid >> 6;
    const int l15 = lane & 15, lg = lane >> 4;
    const int wr = wid >> 1, wc = wid & 1;
    const int bm = blockIdx.y, bn = blockIdx.x;
    const size_t arow0 = (size_t)bm * 128;
    const size_t brow0 = (size_t)bn * 128;

    f32x4 acc[4][4] = {};

    const int nk = K >> 5;
    for (int kt = 0; kt < nk; ++kt) {
        __syncthreads();
        {
            const int k0 = kt * 32;
#pragma unroll
            for (int p = 0; p < 2; ++p) {
                int idx = p * 256 + tid;
                int row = idx >> 2;
                int cc = (idx & 3) * 8;
                const __hip_bfloat16* ga = A + (arow0 + row) * (size_t)K + k0 + cc;
                const __hip_bfloat16* gb = Bt + (brow0 + row) * (size_t)K + k0 + cc;
                __builtin_amdgcn_global_load_lds(
                    (const __attribute__((address_space(1))) void*)ga,
                    (__attribute__((address_space(3))) void*)(&As[idx * 8]), 16, 0, 0);
                __builtin_amdgcn_global_load_lds(
                    (const __attribute__((address_space(1))) void*)gb,
                    (__attribute__((address_space(3))) void*)(&Bs[idx * 8]), 16, 0, 0);
            }
        }
        __syncthreads();
        bf16x8 af[4], bfr[4];
#pragma unroll
        for (int m = 0; m < 4; ++m)
            af[m] = *reinterpret_cast<const bf16x8*>(&As[(wr * 64 + m * 16 + l15) * 32 + lg * 8]);
#pragma unroll
        for (int n = 0; n < 4; ++n)
            bfr[n] = *reinterpret_cast<const bf16x8*>(&Bs[(wc * 64 + n * 16 + l15) * 32 + lg * 8]);
#pragma unroll
        for (int m = 0; m < 4; ++m)
#pragma unroll
            for (int n = 0; n < 4; ++n)
                acc[m][n] = __builtin_amdgcn_mfma_f32_16x16x32_bf16(af[m], bfr[n], acc[m][n], 0, 0, 0);
    }

#pragma unroll
    for (int m = 0; m < 4; ++m) {
#pragma unroll
        for (int n = 0; n < 4; ++n) {
#pragma unroll
            for (int j = 0; j < 4; ++j) {
                int row = bm * 128 + wr * 64 + m * 16 + lg * 4 + j;
                int col = bn * 128 + wc * 64 + n * 16 + l15;
                if (OUT_BF16)
                    Cb[(size_t)row * N + col] = __float2bfloat16(acc[m][n][j]);
                else
                    Cf[(size_t)row * N + col] = acc[m][n][j];
            }
        }
    }
}

// ---------------------------------------------------------------------------
// Flash attention (causal). qkv: [B*T][3072] bf16 (q|k|v each 1024 cols,
// head h at col h*64). y: [B*T][1024] bf16.
// One wave per 16 query rows; 4 independent waves per block. Per 32-key tile:
// QK^T = 4 MFMA (2 col-groups x 2 d-halves), online softmax (16-lane
// shfl_xor reduces), P -> LDS (C-layout) -> bf16x8 A-frag, PV = 4 MFMA.
// ---------------------------------------------------------------------------
__global__ __launch_bounds__(256) void attn_k(const __hip_bfloat16* __restrict__ qkv,
                                              __hip_bfloat16* __restrict__ y) {
    constexpr int TT = 2048;
    constexpr int S3C = 3072;
    const int qt = blockIdx.x;  // 0..31
    const int bh = blockIdx.y;  // 0..63
    const int b = bh >> 4, h = bh & 15;
    const int wid = threadIdx.x >> 6, lane = threadIdx.x & 63;
    const int l15 = lane & 15, lg = lane >> 4;
    const int qbase = qt * 64 + wid * 16;

    __shared__ __attribute__((aligned(16))) __hip_bfloat16 Pl[4][16 * 32];
    __hip_bfloat16* P = &Pl[wid][0];

    const __hip_bfloat16* base = qkv + (size_t)b * TT * S3C;
    const int qo = h * 64, ko = 1024 + h * 64, vo = 2048 + h * 64;

    bf16x8 aq[2];
    {
        const __hip_bfloat16* qp = base + (size_t)(qbase + l15) * S3C + qo + lg * 8;
        aq[0] = *reinterpret_cast<const bf16x8*>(qp);
        aq[1] = *reinterpret_cast<const bf16x8*>(qp + 32);
    }

    float mrow[4], lrow[4];
    f32x4 acc[4] = {};
#pragma unroll
    for (int j = 0; j < 4; ++j) {
        mrow[j] = -1e30f;
        lrow[j] = 0.f;
    }

    const float scale = 0.03125f;  // 1/sqrt(1024)
    const int ntile = ((qbase + 15) >> 5) + 1;

    for (int kt = 0; kt < ntile; ++kt) {
        const int kb = kt * 32;
        // ---- QK^T ----
        f32x4 s[2];
#pragma unroll
        for (int cg = 0; cg < 2; ++cg) {
            const __hip_bfloat16* kp = base + (size_t)(kb + cg * 16 + l15) * S3C + ko + lg * 8;
            bf16x8 k0 = *reinterpret_cast<const bf16x8*>(kp);
            bf16x8 k1 = *reinterpret_cast<const bf16x8*>(kp + 32);
            f32x4 z = {0.f, 0.f, 0.f, 0.f};
            z = __builtin_amdgcn_mfma_f32_16x16x32_bf16(aq[0], k0, z, 0, 0, 0);
            z = __builtin_amdgcn_mfma_f32_16x16x32_bf16(aq[1], k1, z, 0, 0, 0);
            s[cg] = z;
        }
        // ---- scale + causal mask ----
        float p[2][4];
#pragma unroll
        for (int cg = 0; cg < 2; ++cg) {
            int key = kb + cg * 16 + l15;
#pragma unroll
            for (int j = 0; j < 4; ++j) {
                int qrow = qbase + lg * 4 + j;
                float v = s[cg][j] * scale;
                p[cg][j] = (key > qrow) ? -1e30f : v;
            }
        }
        // ---- online softmax (per row j; rows replicated across 16 lanes) ----
        float rescale[4];
#pragma unroll
        for (int j = 0; j < 4; ++j) {
            float tm = fmaxf(p[0][j], p[1][j]);
#pragma unroll
            for (int off = 1; off < 16; off <<= 1)
                tm = fmaxf(tm, __shfl_xor(tm, off, 64));
            float mn = fmaxf(mrow[j], tm);
            float rs = __expf(mrow[j] - mn);
            float p0 = __expf(p[0][j] - mn);
            float p1 = __expf(p[1][j] - mn);
            p[0][j] = p0;
            p[1][j] = p1;
            float sum = p0 + p1;
#pragma unroll
            for (int off = 1; off < 16; off <<= 1)
                sum += __shfl_xor(sum, off, 64);
            lrow[j] = lrow[j] * rs + sum;
            mrow[j] = mn;
            rescale[j] = rs;
        }
#pragma unroll
        for (int dg = 0; dg < 4; ++dg)
#pragma unroll
            for (int j = 0; j < 4; ++j)
                acc[dg][j] *= rescale[j];
        // ---- P: C-layout -> LDS -> A-layout (wave-synchronous) ----
#pragma unroll
        for (int cg = 0; cg < 2; ++cg)
#pragma unroll
            for (int j = 0; j < 4; ++j)
                P[(lg * 4 + j) * 32 + cg * 16 + l15] = __float2bfloat16(p[cg][j]);
        __builtin_amdgcn_s_waitcnt(0);
        bf16x8 pa = *reinterpret_cast<const bf16x8*>(&P[l15 * 32 + lg * 8]);
        // ---- PV ----
        const __hip_bfloat16* vp = base + (size_t)(kb + lg * 8) * S3C + vo + l15;
#pragma unroll
        for (int dg = 0; dg < 4; ++dg) {
            bf16x8 bv;
#pragma unroll
            for (int j = 0; j < 8; ++j)
                bv[j] = *reinterpret_cast<const __bf16*>(vp + (size_t)j * S3C + dg * 16);
            acc[dg] = __builtin_amdgcn_mfma_f32_16x16x32_bf16(pa, bv, acc[dg], 0, 0, 0);
        }
    }

    // ---- epilogue: y[b*T + t][h*64 + d] = acc / lsum ----
#pragma unroll
    for (int dg = 0; dg < 4; ++dg)
#pragma unroll
        for (int j = 0; j < 4; ++j) {
            int t = qbase + lg * 4 + j;
            float o = acc[dg][j] / lrow[j];
            y[((size_t)(b * TT + t)) * 1024 + h * 64 + dg * 16 + l15] = __float2bfloat16(o);
        }
}

// ---------------------------------------------------------------------------
extern "C" void kernel_launch(void* const* d_in, const int* in_sizes, int n_in,
                              void* d_out, int out_size, void* d_ws, size_t ws_size,
                              hipStream_t stream) {
    const float* x = (const float*)d_in[0];   // [4,2048,1024]
    const float* Wa = (const float*)d_in[1];  // [1024,3072]
    const float* Wp = (const float*)d_in[2];  // [1024,1024]
    float* out = (float*)d_out;               // [4,2048,1024] fp32

    __hip_bfloat16* ws = (__hip_bfloat16*)d_ws;
    __hip_bfloat16* x_bf = ws;                          // 8192*1024
    __hip_bfloat16* WaT = x_bf + (size_t)8192 * 1024;   // 3072*1024 (W_attn^T)
    __hip_bfloat16* WpT = WaT + (size_t)3072 * 1024;    // 1024*1024 (W_proj^T)
    __hip_bfloat16* qkv = WpT + (size_t)1024 * 1024;    // 8192*3072
    __hip_bfloat16* ybf = qkv + (size_t)8192 * 3072;    // 8192*1024

    cvt_f32_to_bf16_k<<<8192, 256, 0, stream>>>(x, x_bf, 2097152);
    transpose_cvt<<<dim3(96, 32), 256, 0, stream>>>(Wa, WaT, 1024, 3072);
    transpose_cvt<<<dim3(32, 32), 256, 0, stream>>>(Wp, WpT, 1024, 1024);
    // qkv = x @ W_attn   (M=8192, N=3072, K=1024)
    gemm_bt<true><<<dim3(24, 64), 256, 0, stream>>>(x_bf, WaT, qkv, nullptr, 8192, 3072, 1024);
    // flash attention -> ybf
    attn_k<<<dim3(32, 64), 256, 0, stream>>>(qkv, ybf);
    // out = y @ W_proj   (M=8192, N=1024, K=1024), fp32 out
    gemm_bt<false><<<dim3(8, 64), 256, 0, stream>>>(ybf, WpT, nullptr, out, 8192, 1024, 1024);
}

// Round 2
// 411.269 us; speedup vs baseline: 1.1593x; 1.1593x over previous
//
#include <hip/hip_runtime.h>
#include <hip/hip_bf16.h>

typedef __bf16 bf16x8 __attribute__((ext_vector_type(8)));
typedef float f32x4 __attribute__((ext_vector_type(4)));

// ---------------------------------------------------------------------------
// fp32 -> bf16 elementwise convert (vectorized: float4 in, ushort4 out)
// ---------------------------------------------------------------------------
__global__ __launch_bounds__(256) void cvt_f32_to_bf16_k(const float* __restrict__ in,
                                                         __hip_bfloat16* __restrict__ out,
                                                         int n4) {
    int i = blockIdx.x * blockDim.x + threadIdx.x;
    if (i < n4) {
        float4 v = reinterpret_cast<const float4*>(in)[i];
        __hip_bfloat16 a = __float2bfloat16(v.x);
        __hip_bfloat16 b = __float2bfloat16(v.y);
        __hip_bfloat16 c = __float2bfloat16(v.z);
        __hip_bfloat16 d = __float2bfloat16(v.w);
        ushort4 o;
        o.x = *reinterpret_cast<unsigned short*>(&a);
        o.y = *reinterpret_cast<unsigned short*>(&b);
        o.z = *reinterpret_cast<unsigned short*>(&c);
        o.w = *reinterpret_cast<unsigned short*>(&d);
        reinterpret_cast<ushort4*>(out)[i] = o;
    }
}

// ---------------------------------------------------------------------------
// fp32 [R][Cn] -> bf16 [Cn][R] transposed convert (LDS 32x32 tile)
// ---------------------------------------------------------------------------
__global__ __launch_bounds__(256) void transpose_cvt(const float* __restrict__ in,
                                                     __hip_bfloat16* __restrict__ out,
                                                     int R, int Cn) {
    __shared__ float tile[32][33];
    const int c0 = blockIdx.x * 32, r0 = blockIdx.y * 32;
    const int tx = threadIdx.x & 31, ty = threadIdx.x >> 5;  // 32 x 8
#pragma unroll
    for (int i = 0; i < 4; ++i)
        tile[ty + i * 8][tx] = in[(size_t)(r0 + ty + i * 8) * Cn + c0 + tx];
    __syncthreads();
#pragma unroll
    for (int i = 0; i < 4; ++i)
        out[(size_t)(c0 + ty + i * 8) * R + r0 + tx] = __float2bfloat16(tile[tx][ty + i * 8]);
}

// ---------------------------------------------------------------------------
// V transpose: qkv V-section [b][t][h*64+d] -> Vt[(b*16+h)*64+d][t]  (bf16)
// ---------------------------------------------------------------------------
__global__ __launch_bounds__(256) void vtrans_k(const __hip_bfloat16* __restrict__ qkv,
                                                __hip_bfloat16* __restrict__ Vt) {
    __shared__ __hip_bfloat16 tile[32][33];
    const int bh = blockIdx.z, b = bh >> 4, h = bh & 15;
    const int tt = blockIdx.x;  // 0..63 (t tile)
    const int dt = blockIdx.y;  // 0..1  (d tile)
    const int tx = threadIdx.x & 31, ty = threadIdx.x >> 5;  // 32 x 8
    const __hip_bfloat16* src = qkv + (size_t)b * 2048 * 3072 + 2048 + h * 64;
#pragma unroll
    for (int i = 0; i < 4; ++i)
        tile[ty + i * 8][tx] = src[(size_t)(tt * 32 + ty + i * 8) * 3072 + dt * 32 + tx];
    __syncthreads();
    __hip_bfloat16* dst = Vt + ((size_t)bh * 64 + dt * 32) * 2048 + tt * 32;
#pragma unroll
    for (int i = 0; i < 4; ++i)
        dst[(size_t)(ty + i * 8) * 2048 + tx] = tile[tx][ty + i * 8];
}

// ---------------------------------------------------------------------------
// bf16 GEMM, C = A[M][K] * B, with B given transposed: Bt[N][K].
// m97 structure: 128x128 tile, BK=32, 4 waves each owning 64x64 (4x4 frags of
// 16x16x32 MFMA), global_load_lds width-16 staging, 2 barriers per K-step.
// ---------------------------------------------------------------------------
template <bool OUT_BF16>
__global__ __launch_bounds__(256) void gemm_bt(const __hip_bfloat16* __restrict__ A,
                                               const __hip_bfloat16* __restrict__ Bt,
                                               __hip_bfloat16* __restrict__ Cb,
                                               float* __restrict__ Cf,
                                               int M, int N, int K) {
    __shared__ __attribute__((aligned(16))) __hip_bfloat16 As[128 * 32];
    __shared__ __attribute__((aligned(16))) __hip_bfloat16 Bs[128 * 32];
    const int tid = threadIdx.x;
    const int lane = tid & 63, wid = tid >> 6;
    const int l15 = lane & 15, lg = lane >> 4;
    const int wr = wid >> 1, wc = wid & 1;
    const int bm = blockIdx.y, bn = blockIdx.x;
    const size_t arow0 = (size_t)bm * 128;
    const size_t brow0 = (size_t)bn * 128;

    f32x4 acc[4][4] = {};

    const int nk = K >> 5;
    for (int kt = 0; kt < nk; ++kt) {
        __syncthreads();
        {
            const int k0 = kt * 32;
#pragma unroll
            for (int p = 0; p < 2; ++p) {
                int idx = p * 256 + tid;
                int row = idx >> 2;
                int cc = (idx & 3) * 8;
                const __hip_bfloat16* ga = A + (arow0 + row) * (size_t)K + k0 + cc;
                const __hip_bfloat16* gb = Bt + (brow0 + row) * (size_t)K + k0 + cc;
                __builtin_amdgcn_global_load_lds(
                    (const __attribute__((address_space(1))) void*)ga,
                    (__attribute__((address_space(3))) void*)(&As[idx * 8]), 16, 0, 0);
                __builtin_amdgcn_global_load_lds(
                    (const __attribute__((address_space(1))) void*)gb,
                    (__attribute__((address_space(3))) void*)(&Bs[idx * 8]), 16, 0, 0);
            }
        }
        __syncthreads();
        bf16x8 af[4], bfr[4];
#pragma unroll
        for (int m = 0; m < 4; ++m)
            af[m] = *reinterpret_cast<const bf16x8*>(&As[(wr * 64 + m * 16 + l15) * 32 + lg * 8]);
#pragma unroll
        for (int n = 0; n < 4; ++n)
            bfr[n] = *reinterpret_cast<const bf16x8*>(&Bs[(wc * 64 + n * 16 + l15) * 32 + lg * 8]);
#pragma unroll
        for (int m = 0; m < 4; ++m)
#pragma unroll
            for (int n = 0; n < 4; ++n)
                acc[m][n] = __builtin_amdgcn_mfma_f32_16x16x32_bf16(af[m], bfr[n], acc[m][n], 0, 0, 0);
    }

#pragma unroll
    for (int m = 0; m < 4; ++m) {
#pragma unroll
        for (int n = 0; n < 4; ++n) {
#pragma unroll
            for (int j = 0; j < 4; ++j) {
                int row = bm * 128 + wr * 64 + m * 16 + lg * 4 + j;
                int col = bn * 128 + wc * 64 + n * 16 + l15;
                if (OUT_BF16)
                    Cb[(size_t)row * N + col] = __float2bfloat16(acc[m][n][j]);
                else
                    Cf[(size_t)row * N + col] = acc[m][n][j];
            }
        }
    }
}

// ---------------------------------------------------------------------------
// Flash attention (causal). qkv: [B*T][3072] bf16 (q|k each 1024 cols at
// h*64). Vt: [(b*16+h)*64+d][2048] bf16 (V transposed). y: [B*T][1024] bf16.
// One wave per 32 query rows (2 m-frags); 4 independent waves per block
// (128 q-rows). Per 32-key tile: QK^T = 8 MFMA, online softmax (16-lane
// shfl_xor reduces), P -> LDS -> A-frags, PV = 8 MFMA with coalesced
// bf16x8 Vt loads.
// ---------------------------------------------------------------------------
__global__ __launch_bounds__(256) void attn_k(const __hip_bfloat16* __restrict__ qkv,
                                              const __hip_bfloat16* __restrict__ Vt,
                                              __hip_bfloat16* __restrict__ y) {
    constexpr int TT = 2048;
    constexpr int S3C = 3072;
    const int qt = blockIdx.x;  // 0..15
    const int bh = blockIdx.y;  // 0..63
    const int b = bh >> 4, h = bh & 15;
    const int wid = threadIdx.x >> 6, lane = threadIdx.x & 63;
    const int l15 = lane & 15, lg = lane >> 4;
    const int qbase = qt * 128 + wid * 32;

    __shared__ __attribute__((aligned(16))) __hip_bfloat16 Pl[4][32 * 32];
    __hip_bfloat16* P = &Pl[wid][0];

    const __hip_bfloat16* base = qkv + (size_t)b * TT * S3C;
    const int qo = h * 64, ko = 1024 + h * 64;
    const __hip_bfloat16* vt = Vt + (size_t)bh * 64 * TT;

    // Q fragments: 2 m-frags x 2 k-halves (d = 0..31, 32..63)
    bf16x8 aq[2][2];
#pragma unroll
    for (int m = 0; m < 2; ++m) {
        const __hip_bfloat16* qp = base + (size_t)(qbase + m * 16 + l15) * S3C + qo + lg * 8;
        aq[m][0] = *reinterpret_cast<const bf16x8*>(qp);
        aq[m][1] = *reinterpret_cast<const bf16x8*>(qp + 32);
    }

    float mrow[2][4], lrow[2][4];
    f32x4 acc[2][4] = {};
#pragma unroll
    for (int m = 0; m < 2; ++m)
#pragma unroll
        for (int j = 0; j < 4; ++j) {
            mrow[m][j] = -1e30f;
            lrow[m][j] = 0.f;
        }

    const float scale = 0.03125f;  // 1/sqrt(1024)
    const int ntile = (qbase >> 5) + 1;

    for (int kt = 0; kt < ntile; ++kt) {
        const int kb = kt * 32;
        // ---- K fragments (shared by both m-frags) ----
        bf16x8 kf[2][2];
#pragma unroll
        for (int cg = 0; cg < 2; ++cg) {
            const __hip_bfloat16* kp = base + (size_t)(kb + cg * 16 + l15) * S3C + ko + lg * 8;
            kf[cg][0] = *reinterpret_cast<const bf16x8*>(kp);
            kf[cg][1] = *reinterpret_cast<const bf16x8*>(kp + 32);
        }
        // ---- QK^T ----
        f32x4 s[2][2];
#pragma unroll
        for (int m = 0; m < 2; ++m)
#pragma unroll
            for (int cg = 0; cg < 2; ++cg) {
                f32x4 z = {0.f, 0.f, 0.f, 0.f};
                z = __builtin_amdgcn_mfma_f32_16x16x32_bf16(aq[m][0], kf[cg][0], z, 0, 0, 0);
                z = __builtin_amdgcn_mfma_f32_16x16x32_bf16(aq[m][1], kf[cg][1], z, 0, 0, 0);
                s[m][cg] = z;
            }
        // ---- scale + causal mask + online softmax ----
        float p[2][2][4];
#pragma unroll
        for (int m = 0; m < 2; ++m)
#pragma unroll
            for (int cg = 0; cg < 2; ++cg) {
                int key = kb + cg * 16 + l15;
#pragma unroll
                for (int j = 0; j < 4; ++j) {
                    int qrow = qbase + m * 16 + lg * 4 + j;
                    float v = s[m][cg][j] * scale;
                    p[m][cg][j] = (key > qrow) ? -1e30f : v;
                }
            }
        float rescale[2][4];
#pragma unroll
        for (int m = 0; m < 2; ++m)
#pragma unroll
            for (int j = 0; j < 4; ++j) {
                float tm = fmaxf(p[m][0][j], p[m][1][j]);
#pragma unroll
                for (int off = 1; off < 16; off <<= 1)
                    tm = fmaxf(tm, __shfl_xor(tm, off, 64));
                float mn = fmaxf(mrow[m][j], tm);
                float rs = __expf(mrow[m][j] - mn);
                float p0 = __expf(p[m][0][j] - mn);
                float p1 = __expf(p[m][1][j] - mn);
                p[m][0][j] = p0;
                p[m][1][j] = p1;
                float sum = p0 + p1;
#pragma unroll
                for (int off = 1; off < 16; off <<= 1)
                    sum += __shfl_xor(sum, off, 64);
                lrow[m][j] = lrow[m][j] * rs + sum;
                mrow[m][j] = mn;
                rescale[m][j] = rs;
            }
#pragma unroll
        for (int m = 0; m < 2; ++m)
#pragma unroll
            for (int dg = 0; dg < 4; ++dg)
#pragma unroll
                for (int j = 0; j < 4; ++j)
                    acc[m][dg][j] *= rescale[m][j];
        // ---- P: C-layout -> LDS -> A-layout (wave-synchronous) ----
#pragma unroll
        for (int m = 0; m < 2; ++m)
#pragma unroll
            for (int cg = 0; cg < 2; ++cg)
#pragma unroll
                for (int j = 0; j < 4; ++j)
                    P[(m * 16 + lg * 4 + j) * 32 + cg * 16 + l15] = __float2bfloat16(p[m][cg][j]);
        asm volatile("s_waitcnt lgkmcnt(0)" ::: "memory");
        __builtin_amdgcn_sched_barrier(0);
        bf16x8 pa[2];
#pragma unroll
        for (int m = 0; m < 2; ++m)
            pa[m] = *reinterpret_cast<const bf16x8*>(&P[(m * 16 + l15) * 32 + lg * 8]);
        // ---- PV: coalesced Vt B-frags ----
#pragma unroll
        for (int dg = 0; dg < 4; ++dg) {
            bf16x8 bv = *reinterpret_cast<const bf16x8*>(&vt[(size_t)(dg * 16 + l15) * TT + kb + lg * 8]);
#pragma unroll
            for (int m = 0; m < 2; ++m)
                acc[m][dg] = __builtin_amdgcn_mfma_f32_16x16x32_bf16(pa[m], bv, acc[m][dg], 0, 0, 0);
        }
    }

    // ---- epilogue ----
#pragma unroll
    for (int m = 0; m < 2; ++m)
#pragma unroll
        for (int dg = 0; dg < 4; ++dg)
#pragma unroll
            for (int j = 0; j < 4; ++j) {
                int t = qbase + m * 16 + lg * 4 + j;
                float o = acc[m][dg][j] / lrow[m][j];
                y[((size_t)(b * TT + t)) * 1024 + h * 64 + dg * 16 + l15] = __float2bfloat16(o);
            }
}

// ---------------------------------------------------------------------------
extern "C" void kernel_launch(void* const* d_in, const int* in_sizes, int n_in,
                              void* d_out, int out_size, void* d_ws, size_t ws_size,
                              hipStream_t stream) {
    const float* x = (const float*)d_in[0];   // [4,2048,1024]
    const float* Wa = (const float*)d_in[1];  // [1024,3072]
    const float* Wp = (const float*)d_in[2];  // [1024,1024]
    float* out = (float*)d_out;               // [4,2048,1024] fp32

    __hip_bfloat16* ws = (__hip_bfloat16*)d_ws;
    __hip_bfloat16* x_bf = ws;                          // 8192*1024 (dead after GEMM1)
    __hip_bfloat16* WaT = x_bf + (size_t)8192 * 1024;   // 3072*1024 (W_attn^T)
    __hip_bfloat16* WpT = WaT + (size_t)3072 * 1024;    // 1024*1024 (W_proj^T)
    __hip_bfloat16* qkv = WpT + (size_t)1024 * 1024;    // 8192*3072
    __hip_bfloat16* ybf = qkv + (size_t)8192 * 3072;    // 8192*1024
    __hip_bfloat16* Vt = x_bf;                          // reuse: 64*64*2048 = 8192*1024

    cvt_f32_to_bf16_k<<<8192, 256, 0, stream>>>(x, x_bf, 2097152);
    transpose_cvt<<<dim3(96, 32), 256, 0, stream>>>(Wa, WaT, 1024, 3072);
    transpose_cvt<<<dim3(32, 32), 256, 0, stream>>>(Wp, WpT, 1024, 1024);
    // qkv = x @ W_attn   (M=8192, N=3072, K=1024)
    gemm_bt<true><<<dim3(24, 64), 256, 0, stream>>>(x_bf, WaT, qkv, nullptr, 8192, 3072, 1024);
    // V^T per head (x_bf is dead now; Vt aliases it)
    vtrans_k<<<dim3(64, 2, 64), 256, 0, stream>>>(qkv, Vt);
    // flash attention -> ybf
    attn_k<<<dim3(16, 64), 256, 0, stream>>>(qkv, Vt, ybf);
    // out = y @ W_proj   (M=8192, N=1024, K=1024), fp32 out
    gemm_bt<false><<<dim3(8, 64), 256, 0, stream>>>(ybf, WpT, nullptr, out, 8192, 1024, 1024);
}

// Round 3
// 259.484 us; speedup vs baseline: 1.8374x; 1.5850x over previous
//
#include <hip/hip_runtime.h>
#include <hip/hip_bf16.h>

typedef __bf16 bf16x8 __attribute__((ext_vector_type(8)));
typedef float f32x4 __attribute__((ext_vector_type(4)));

// ---------------------------------------------------------------------------
// fp32 -> bf16 elementwise convert (vectorized: float4 in, ushort4 out)
// ---------------------------------------------------------------------------
__global__ __launch_bounds__(256) void cvt_f32_to_bf16_k(const float* __restrict__ in,
                                                         __hip_bfloat16* __restrict__ out,
                                                         int n4) {
    int i = blockIdx.x * blockDim.x + threadIdx.x;
    if (i < n4) {
        float4 v = reinterpret_cast<const float4*>(in)[i];
        __hip_bfloat16 a = __float2bfloat16(v.x);
        __hip_bfloat16 b = __float2bfloat16(v.y);
        __hip_bfloat16 c = __float2bfloat16(v.z);
        __hip_bfloat16 d = __float2bfloat16(v.w);
        ushort4 o;
        o.x = *reinterpret_cast<unsigned short*>(&a);
        o.y = *reinterpret_cast<unsigned short*>(&b);
        o.z = *reinterpret_cast<unsigned short*>(&c);
        o.w = *reinterpret_cast<unsigned short*>(&d);
        reinterpret_cast<ushort4*>(out)[i] = o;
    }
}

// ---------------------------------------------------------------------------
// fp32 [R][Cn] -> bf16 [Cn][R] transposed convert (LDS 32x32 tile)
// ---------------------------------------------------------------------------
__global__ __launch_bounds__(256) void transpose_cvt(const float* __restrict__ in,
                                                     __hip_bfloat16* __restrict__ out,
                                                     int R, int Cn) {
    __shared__ float tile[32][33];
    const int c0 = blockIdx.x * 32, r0 = blockIdx.y * 32;
    const int tx = threadIdx.x & 31, ty = threadIdx.x >> 5;  // 32 x 8
#pragma unroll
    for (int i = 0; i < 4; ++i)
        tile[ty + i * 8][tx] = in[(size_t)(r0 + ty + i * 8) * Cn + c0 + tx];
    __syncthreads();
#pragma unroll
    for (int i = 0; i < 4; ++i)
        out[(size_t)(c0 + ty + i * 8) * R + r0 + tx] = __float2bfloat16(tile[tx][ty + i * 8]);
}

// ---------------------------------------------------------------------------
// V transpose: qkv V-section [b][t][h*64+d] -> Vt[(b*16+h)*64+d][t]  (bf16)
// ---------------------------------------------------------------------------
__global__ __launch_bounds__(256) void vtrans_k(const __hip_bfloat16* __restrict__ qkv,
                                                __hip_bfloat16* __restrict__ Vt) {
    __shared__ __hip_bfloat16 tile[32][33];
    const int bh = blockIdx.z, b = bh >> 4, h = bh & 15;
    const int tt = blockIdx.x;  // 0..63 (t tile)
    const int dt = blockIdx.y;  // 0..1  (d tile)
    const int tx = threadIdx.x & 31, ty = threadIdx.x >> 5;  // 32 x 8
    const __hip_bfloat16* src = qkv + (size_t)b * 2048 * 3072 + 2048 + h * 64;
#pragma unroll
    for (int i = 0; i < 4; ++i)
        tile[ty + i * 8][tx] = src[(size_t)(tt * 32 + ty + i * 8) * 3072 + dt * 32 + tx];
    __syncthreads();
    __hip_bfloat16* dst = Vt + ((size_t)bh * 64 + dt * 32) * 2048 + tt * 32;
#pragma unroll
    for (int i = 0; i < 4; ++i)
        dst[(size_t)(ty + i * 8) * 2048 + tx] = tile[tx][ty + i * 8];
}

// ---------------------------------------------------------------------------
// bf16 GEMM, C = A[M][K] * B, with B given transposed: Bt[N][K].
// m97 structure: 128x128 tile, BK=32, 4 waves each owning 64x64 (4x4 frags of
// 16x16x32 MFMA), global_load_lds width-16 staging, 2 barriers per K-step.
// ---------------------------------------------------------------------------
template <bool OUT_BF16>
__global__ __launch_bounds__(256) void gemm_bt(const __hip_bfloat16* __restrict__ A,
                                               const __hip_bfloat16* __restrict__ Bt,
                                               __hip_bfloat16* __restrict__ Cb,
                                               float* __restrict__ Cf,
                                               int M, int N, int K) {
    __shared__ __attribute__((aligned(16))) __hip_bfloat16 As[128 * 32];
    __shared__ __attribute__((aligned(16))) __hip_bfloat16 Bs[128 * 32];
    const int tid = threadIdx.x;
    const int lane = tid & 63, wid = tid >> 6;
    const int l15 = lane & 15, lg = lane >> 4;
    const int wr = wid >> 1, wc = wid & 1;
    const int bm = blockIdx.y, bn = blockIdx.x;
    const size_t arow0 = (size_t)bm * 128;
    const size_t brow0 = (size_t)bn * 128;

    f32x4 acc[4][4] = {};

    const int nk = K >> 5;
    for (int kt = 0; kt < nk; ++kt) {
        __syncthreads();
        {
            const int k0 = kt * 32;
#pragma unroll
            for (int p = 0; p < 2; ++p) {
                int idx = p * 256 + tid;
                int row = idx >> 2;
                int cc = (idx & 3) * 8;
                const __hip_bfloat16* ga = A + (arow0 + row) * (size_t)K + k0 + cc;
                const __hip_bfloat16* gb = Bt + (brow0 + row) * (size_t)K + k0 + cc;
                __builtin_amdgcn_global_load_lds(
                    (const __attribute__((address_space(1))) void*)ga,
                    (__attribute__((address_space(3))) void*)(&As[idx * 8]), 16, 0, 0);
                __builtin_amdgcn_global_load_lds(
                    (const __attribute__((address_space(1))) void*)gb,
                    (__attribute__((address_space(3))) void*)(&Bs[idx * 8]), 16, 0, 0);
            }
        }
        __syncthreads();
        bf16x8 af[4], bfr[4];
#pragma unroll
        for (int m = 0; m < 4; ++m)
            af[m] = *reinterpret_cast<const bf16x8*>(&As[(wr * 64 + m * 16 + l15) * 32 + lg * 8]);
#pragma unroll
        for (int n = 0; n < 4; ++n)
            bfr[n] = *reinterpret_cast<const bf16x8*>(&Bs[(wc * 64 + n * 16 + l15) * 32 + lg * 8]);
#pragma unroll
        for (int m = 0; m < 4; ++m)
#pragma unroll
            for (int n = 0; n < 4; ++n)
                acc[m][n] = __builtin_amdgcn_mfma_f32_16x16x32_bf16(af[m], bfr[n], acc[m][n], 0, 0, 0);
    }

#pragma unroll
    for (int m = 0; m < 4; ++m) {
#pragma unroll
        for (int n = 0; n < 4; ++n) {
#pragma unroll
            for (int j = 0; j < 4; ++j) {
                int row = bm * 128 + wr * 64 + m * 16 + lg * 4 + j;
                int col = bn * 128 + wc * 64 + n * 16 + l15;
                if (OUT_BF16)
                    Cb[(size_t)row * N + col] = __float2bfloat16(acc[m][n][j]);
                else
                    Cf[(size_t)row * N + col] = acc[m][n][j];
            }
        }
    }
}

// ---------------------------------------------------------------------------
// Flash attention (causal), swapped-QK^T structure.
// qkv: [B*T][3072] bf16 (q at h*64, k at 1024+h*64). Vt: [(b*16+h)*64+d][2048].
// One wave = 32 q-rows (2 m-frags of 16), KVBLK = 64 keys per round.
// QK^T computed as mfma(K, Q) -> scores land [key in regs][q = lane&15]:
// softmax reductions are in-lane trees + 2 shfl_xor steps (lanes^16, ^32).
// P round-trips through a per-wave swizzled LDS buffer to become the PV
// A-fragment. K for tile t+1 prefetched during softmax of tile t.
// ---------------------------------------------------------------------------
__global__ __launch_bounds__(256) void attn_k(const __hip_bfloat16* __restrict__ qkv,
                                              const __hip_bfloat16* __restrict__ Vt,
                                              __hip_bfloat16* __restrict__ y) {
    constexpr int TT = 2048;
    constexpr int S3C = 3072;
    const int bh = blockIdx.x;       // 0..63 (fastest: balanced dispatch)
    const int qt = 15 - blockIdx.y;  // heavy q-tiles dispatched first
    const int b = bh >> 4, h = bh & 15;
    const int wid = threadIdx.x >> 6, lane = threadIdx.x & 63;
    const int l15 = lane & 15, lg = lane >> 4;
    const int qbase = qt * 128 + wid * 32;

    // per-wave P buffer: [32 q][64 keys] bf16, byte = q*128 + 2*(key ^ ((q&7)<<3))
    __shared__ __attribute__((aligned(16))) char Pl[4][32 * 64 * 2];
    char* P = &Pl[wid][0];

    const __hip_bfloat16* base = qkv + (size_t)b * TT * S3C;
    const int qo = h * 64, ko = 1024 + h * 64;
    const __hip_bfloat16* vt = Vt + (size_t)bh * 64 * TT;

    // Q B-fragments: [m][half]: Q[q=qbase+m*16+l15][d=half*32+lg*8 ..]
    bf16x8 aq[2][2];
#pragma unroll
    for (int m = 0; m < 2; ++m) {
        const __hip_bfloat16* qp = base + (size_t)(qbase + m * 16 + l15) * S3C + qo + lg * 8;
        aq[m][0] = *reinterpret_cast<const bf16x8*>(qp);
        aq[m][1] = *reinterpret_cast<const bf16x8*>(qp + 32);
    }

    float mrow[2] = {-1e30f, -1e30f}, lrow[2] = {0.f, 0.f};
    f32x4 acc[2][4] = {};  // [m][dg]: row=q(lg*4+j), col=d(dg*16+l15)

    const float scale = 0.03125f;  // 1/sqrt(1024)
    const int ntile = ((qbase + 31) >> 6) + 1;

    // K A-fragments: [cg][half]: K[key=kb+cg*16+l15][d=half*32+lg*8 ..]
    bf16x8 kf[4][2];
#pragma unroll
    for (int cg = 0; cg < 4; ++cg) {
        const __hip_bfloat16* kp = base + (size_t)(cg * 16 + l15) * S3C + ko + lg * 8;
        kf[cg][0] = *reinterpret_cast<const bf16x8*>(kp);
        kf[cg][1] = *reinterpret_cast<const bf16x8*>(kp + 32);
    }

    for (int kt = 0; kt < ntile; ++kt) {
        const int kb = kt * 64;
        // ---- QK^T (swapped): s[m][cg][j] = S[key=kb+cg*16+lg*4+j][q=qbase+m*16+l15]
        f32x4 s[2][4];
#pragma unroll
        for (int m = 0; m < 2; ++m)
#pragma unroll
            for (int cg = 0; cg < 4; ++cg) {
                f32x4 z = {0.f, 0.f, 0.f, 0.f};
                z = __builtin_amdgcn_mfma_f32_16x16x32_bf16(kf[cg][0], aq[m][0], z, 0, 0, 0);
                z = __builtin_amdgcn_mfma_f32_16x16x32_bf16(kf[cg][1], aq[m][1], z, 0, 0, 0);
                s[m][cg] = z;
            }
        // ---- prefetch next K tile (hidden under softmax)
        bf16x8 kn[4][2];
        const bool more = (kt + 1 < ntile);
        if (more) {
            const int kb2 = kb + 64;
#pragma unroll
            for (int cg = 0; cg < 4; ++cg) {
                const __hip_bfloat16* kp = base + (size_t)(kb2 + cg * 16 + l15) * S3C + ko + lg * 8;
                kn[cg][0] = *reinterpret_cast<const bf16x8*>(kp);
                kn[cg][1] = *reinterpret_cast<const bf16x8*>(kp + 32);
            }
        }
        // ---- scale + causal mask (only partial tiles need the mask)
        float p[2][4][4];
        const bool needmask = (kb + 63 > qbase);
#pragma unroll
        for (int m = 0; m < 2; ++m)
#pragma unroll
            for (int cg = 0; cg < 4; ++cg)
#pragma unroll
                for (int j = 0; j < 4; ++j) {
                    float v = s[m][cg][j] * scale;
                    if (needmask) {
                        int key = kb + cg * 16 + lg * 4 + j;
                        int qrow = qbase + m * 16 + l15;
                        v = (key > qrow) ? -1e30f : v;
                    }
                    p[m][cg][j] = v;
                }
        // ---- online softmax, per m-frag (stats live at lane l15 = q)
        float rs[2];
#pragma unroll
        for (int m = 0; m < 2; ++m) {
            float c0 = fmaxf(fmaxf(p[m][0][0], p[m][0][1]), fmaxf(p[m][0][2], p[m][0][3]));
            float c1 = fmaxf(fmaxf(p[m][1][0], p[m][1][1]), fmaxf(p[m][1][2], p[m][1][3]));
            float c2 = fmaxf(fmaxf(p[m][2][0], p[m][2][1]), fmaxf(p[m][2][2], p[m][2][3]));
            float c3 = fmaxf(fmaxf(p[m][3][0], p[m][3][1]), fmaxf(p[m][3][2], p[m][3][3]));
            float tm = fmaxf(fmaxf(c0, c1), fmaxf(c2, c3));
            tm = fmaxf(tm, __shfl_xor(tm, 16, 64));
            tm = fmaxf(tm, __shfl_xor(tm, 32, 64));
            float mn = fmaxf(mrow[m], tm);
            rs[m] = __expf(mrow[m] - mn);
            float ssum = 0.f;
#pragma unroll
            for (int cg = 0; cg < 4; ++cg) {
                float e0 = __expf(p[m][cg][0] - mn);
                float e1 = __expf(p[m][cg][1] - mn);
                float e2 = __expf(p[m][cg][2] - mn);
                float e3 = __expf(p[m][cg][3] - mn);
                p[m][cg][0] = e0; p[m][cg][1] = e1; p[m][cg][2] = e2; p[m][cg][3] = e3;
                ssum += (e0 + e1) + (e2 + e3);
            }
            ssum += __shfl_xor(ssum, 16, 64);
            ssum += __shfl_xor(ssum, 32, 64);
            lrow[m] = lrow[m] * rs[m] + ssum;
            mrow[m] = mn;
        }
        // ---- rescale acc (redistribute rs from lane l15=q to acc row lg*4+j)
#pragma unroll
        for (int m = 0; m < 2; ++m)
#pragma unroll
            for (int j = 0; j < 4; ++j) {
                float r4 = __shfl(rs[m], lg * 4 + j, 64);
#pragma unroll
                for (int dg = 0; dg < 4; ++dg)
                    acc[m][dg][j] *= r4;
            }
        // ---- P -> LDS (packed b64, swizzled)
#pragma unroll
        for (int m = 0; m < 2; ++m) {
            const int ql = m * 16 + l15;
            const int swz = (ql & 7) << 3;
#pragma unroll
            for (int cg = 0; cg < 4; ++cg) {
                __hip_bfloat16 h0 = __float2bfloat16(p[m][cg][0]);
                __hip_bfloat16 h1 = __float2bfloat16(p[m][cg][1]);
                __hip_bfloat16 h2 = __float2bfloat16(p[m][cg][2]);
                __hip_bfloat16 h3 = __float2bfloat16(p[m][cg][3]);
                uint2 u;
                u.x = (unsigned)*(unsigned short*)&h0 | ((unsigned)*(unsigned short*)&h1 << 16);
                u.y = (unsigned)*(unsigned short*)&h2 | ((unsigned)*(unsigned short*)&h3 << 16);
                int keyx = (cg * 16 + lg * 4) ^ swz;
                *reinterpret_cast<uint2*>(P + ql * 128 + keyx * 2) = u;
            }
        }
        // ---- V B-fragments (issued before the LDS wait; independent of P)
        bf16x8 vb[4][2];
#pragma unroll
        for (int dg = 0; dg < 4; ++dg)
#pragma unroll
            for (int ks = 0; ks < 2; ++ks)
                vb[dg][ks] = *reinterpret_cast<const bf16x8*>(
                    &vt[(size_t)(dg * 16 + l15) * TT + kb + ks * 32 + lg * 8]);
        asm volatile("s_waitcnt lgkmcnt(0)" ::: "memory");
        __builtin_amdgcn_sched_barrier(0);
        // ---- P A-fragments + PV
        bf16x8 pa[2][2];
#pragma unroll
        for (int m = 0; m < 2; ++m) {
            const int ql = m * 16 + l15;
            const int swz = (ql & 7) << 3;
#pragma unroll
            for (int ks = 0; ks < 2; ++ks) {
                int keyx = (ks * 32 + lg * 8) ^ swz;
                pa[m][ks] = *reinterpret_cast<const bf16x8*>(P + ql * 128 + keyx * 2);
            }
        }
#pragma unroll
        for (int ks = 0; ks < 2; ++ks)
#pragma unroll
            for (int dg = 0; dg < 4; ++dg)
#pragma unroll
                for (int m = 0; m < 2; ++m)
                    acc[m][dg] = __builtin_amdgcn_mfma_f32_16x16x32_bf16(pa[m][ks], vb[dg][ks],
                                                                         acc[m][dg], 0, 0, 0);
        // ---- advance prefetched K
        if (more) {
#pragma unroll
            for (int cg = 0; cg < 4; ++cg) {
                kf[cg][0] = kn[cg][0];
                kf[cg][1] = kn[cg][1];
            }
        }
    }

    // ---- epilogue: redistribute lrow, divide, store
#pragma unroll
    for (int m = 0; m < 2; ++m)
#pragma unroll
        for (int j = 0; j < 4; ++j) {
            float lr = __shfl(lrow[m], lg * 4 + j, 64);
            float inv = 1.f / lr;
            int t = qbase + m * 16 + lg * 4 + j;
#pragma unroll
            for (int dg = 0; dg < 4; ++dg) {
                float o = acc[m][dg][j] * inv;
                y[((size_t)(b * TT + t)) * 1024 + h * 64 + dg * 16 + l15] = __float2bfloat16(o);
            }
        }
}

// ---------------------------------------------------------------------------
extern "C" void kernel_launch(void* const* d_in, const int* in_sizes, int n_in,
                              void* d_out, int out_size, void* d_ws, size_t ws_size,
                              hipStream_t stream) {
    const float* x = (const float*)d_in[0];   // [4,2048,1024]
    const float* Wa = (const float*)d_in[1];  // [1024,3072]
    const float* Wp = (const float*)d_in[2];  // [1024,1024]
    float* out = (float*)d_out;               // [4,2048,1024] fp32

    __hip_bfloat16* ws = (__hip_bfloat16*)d_ws;
    __hip_bfloat16* x_bf = ws;                          // 8192*1024 (dead after GEMM1)
    __hip_bfloat16* WaT = x_bf + (size_t)8192 * 1024;   // 3072*1024 (W_attn^T)
    __hip_bfloat16* WpT = WaT + (size_t)3072 * 1024;    // 1024*1024 (W_proj^T)
    __hip_bfloat16* qkv = WpT + (size_t)1024 * 1024;    // 8192*3072
    __hip_bfloat16* ybf = qkv + (size_t)8192 * 3072;    // 8192*1024
    __hip_bfloat16* Vt = x_bf;                          // reuse: 64*64*2048 = 8192*1024

    cvt_f32_to_bf16_k<<<8192, 256, 0, stream>>>(x, x_bf, 2097152);
    transpose_cvt<<<dim3(96, 32), 256, 0, stream>>>(Wa, WaT, 1024, 3072);
    transpose_cvt<<<dim3(32, 32), 256, 0, stream>>>(Wp, WpT, 1024, 1024);
    // qkv = x @ W_attn   (M=8192, N=3072, K=1024)
    gemm_bt<true><<<dim3(24, 64), 256, 0, stream>>>(x_bf, WaT, qkv, nullptr, 8192, 3072, 1024);
    // V^T per head (x_bf is dead now; Vt aliases it)
    vtrans_k<<<dim3(64, 2, 64), 256, 0, stream>>>(qkv, Vt);
    // flash attention -> ybf
    attn_k<<<dim3(64, 16), 256, 0, stream>>>(qkv, Vt, ybf);
    // out = y @ W_proj   (M=8192, N=1024, K=1024), fp32 out
    gemm_bt<false><<<dim3(8, 64), 256, 0, stream>>>(ybf, WpT, nullptr, out, 8192, 1024, 1024);
}

// Round 4
// 224.820 us; speedup vs baseline: 2.1207x; 1.1542x over previous
//
#include <hip/hip_runtime.h>
#include <hip/hip_bf16.h>

typedef __bf16 bf16x8 __attribute__((ext_vector_type(8)));
typedef float f32x4 __attribute__((ext_vector_type(4)));

// ---------------------------------------------------------------------------
// fp32 -> bf16 elementwise convert (vectorized: float4 in, ushort4 out)
// ---------------------------------------------------------------------------
__global__ __launch_bounds__(256) void cvt_f32_to_bf16_k(const float* __restrict__ in,
                                                         __hip_bfloat16* __restrict__ out,
                                                         int n4) {
    int i = blockIdx.x * blockDim.x + threadIdx.x;
    if (i < n4) {
        float4 v = reinterpret_cast<const float4*>(in)[i];
        __hip_bfloat16 a = __float2bfloat16(v.x);
        __hip_bfloat16 b = __float2bfloat16(v.y);
        __hip_bfloat16 c = __float2bfloat16(v.z);
        __hip_bfloat16 d = __float2bfloat16(v.w);
        ushort4 o;
        o.x = *reinterpret_cast<unsigned short*>(&a);
        o.y = *reinterpret_cast<unsigned short*>(&b);
        o.z = *reinterpret_cast<unsigned short*>(&c);
        o.w = *reinterpret_cast<unsigned short*>(&d);
        reinterpret_cast<ushort4*>(out)[i] = o;
    }
}

// ---------------------------------------------------------------------------
// fp32 [R][Cn] -> bf16 [Cn][R] transposed convert (LDS 32x32 tile)
// ---------------------------------------------------------------------------
__global__ __launch_bounds__(256) void transpose_cvt(const float* __restrict__ in,
                                                     __hip_bfloat16* __restrict__ out,
                                                     int R, int Cn) {
    __shared__ float tile[32][33];
    const int c0 = blockIdx.x * 32, r0 = blockIdx.y * 32;
    const int tx = threadIdx.x & 31, ty = threadIdx.x >> 5;  // 32 x 8
#pragma unroll
    for (int i = 0; i < 4; ++i)
        tile[ty + i * 8][tx] = in[(size_t)(r0 + ty + i * 8) * Cn + c0 + tx];
    __syncthreads();
#pragma unroll
    for (int i = 0; i < 4; ++i)
        out[(size_t)(c0 + ty + i * 8) * R + r0 + tx] = __float2bfloat16(tile[tx][ty + i * 8]);
}

// ---------------------------------------------------------------------------
// V transpose: qkv V-section [b][t][h*64+d] -> Vt[(b*16+h)*64+d][t]  (bf16)
// ---------------------------------------------------------------------------
__global__ __launch_bounds__(256) void vtrans_k(const __hip_bfloat16* __restrict__ qkv,
                                                __hip_bfloat16* __restrict__ Vt) {
    __shared__ __hip_bfloat16 tile[32][33];
    const int bh = blockIdx.z, b = bh >> 4, h = bh & 15;
    const int tt = blockIdx.x;  // 0..63 (t tile)
    const int dt = blockIdx.y;  // 0..1  (d tile)
    const int tx = threadIdx.x & 31, ty = threadIdx.x >> 5;  // 32 x 8
    const __hip_bfloat16* src = qkv + (size_t)b * 2048 * 3072 + 2048 + h * 64;
#pragma unroll
    for (int i = 0; i < 4; ++i)
        tile[ty + i * 8][tx] = src[(size_t)(tt * 32 + ty + i * 8) * 3072 + dt * 32 + tx];
    __syncthreads();
    __hip_bfloat16* dst = Vt + ((size_t)bh * 64 + dt * 32) * 2048 + tt * 32;
#pragma unroll
    for (int i = 0; i < 4; ++i)
        dst[(size_t)(ty + i * 8) * 2048 + tx] = tile[tx][ty + i * 8];
}

// ---------------------------------------------------------------------------
// bf16 GEMM, C = A[M][K] * B, with B given transposed: Bt[N][K].
// m97 structure: 128x128 tile, BK=32, 4 waves each owning 64x64.
// ---------------------------------------------------------------------------
template <bool OUT_BF16>
__global__ __launch_bounds__(256) void gemm_bt(const __hip_bfloat16* __restrict__ A,
                                               const __hip_bfloat16* __restrict__ Bt,
                                               __hip_bfloat16* __restrict__ Cb,
                                               float* __restrict__ Cf,
                                               int M, int N, int K) {
    __shared__ __attribute__((aligned(16))) __hip_bfloat16 As[128 * 32];
    __shared__ __attribute__((aligned(16))) __hip_bfloat16 Bs[128 * 32];
    const int tid = threadIdx.x;
    const int lane = tid & 63, wid = tid >> 6;
    const int l15 = lane & 15, lg = lane >> 4;
    const int wr = wid >> 1, wc = wid & 1;
    const int bm = blockIdx.y, bn = blockIdx.x;
    const size_t arow0 = (size_t)bm * 128;
    const size_t brow0 = (size_t)bn * 128;

    f32x4 acc[4][4] = {};

    const int nk = K >> 5;
    for (int kt = 0; kt < nk; ++kt) {
        __syncthreads();
        {
            const int k0 = kt * 32;
#pragma unroll
            for (int p = 0; p < 2; ++p) {
                int idx = p * 256 + tid;
                int row = idx >> 2;
                int cc = (idx & 3) * 8;
                const __hip_bfloat16* ga = A + (arow0 + row) * (size_t)K + k0 + cc;
                const __hip_bfloat16* gb = Bt + (brow0 + row) * (size_t)K + k0 + cc;
                __builtin_amdgcn_global_load_lds(
                    (const __attribute__((address_space(1))) void*)ga,
                    (__attribute__((address_space(3))) void*)(&As[idx * 8]), 16, 0, 0);
                __builtin_amdgcn_global_load_lds(
                    (const __attribute__((address_space(1))) void*)gb,
                    (__attribute__((address_space(3))) void*)(&Bs[idx * 8]), 16, 0, 0);
            }
        }
        __syncthreads();
        bf16x8 af[4], bfr[4];
#pragma unroll
        for (int m = 0; m < 4; ++m)
            af[m] = *reinterpret_cast<const bf16x8*>(&As[(wr * 64 + m * 16 + l15) * 32 + lg * 8]);
#pragma unroll
        for (int n = 0; n < 4; ++n)
            bfr[n] = *reinterpret_cast<const bf16x8*>(&Bs[(wc * 64 + n * 16 + l15) * 32 + lg * 8]);
#pragma unroll
        for (int m = 0; m < 4; ++m)
#pragma unroll
            for (int n = 0; n < 4; ++n)
                acc[m][n] = __builtin_amdgcn_mfma_f32_16x16x32_bf16(af[m], bfr[n], acc[m][n], 0, 0, 0);
    }

#pragma unroll
    for (int m = 0; m < 4; ++m) {
#pragma unroll
        for (int n = 0; n < 4; ++n) {
#pragma unroll
            for (int j = 0; j < 4; ++j) {
                int row = bm * 128 + wr * 64 + m * 16 + lg * 4 + j;
                int col = bn * 128 + wc * 64 + n * 16 + l15;
                if (OUT_BF16)
                    Cb[(size_t)row * N + col] = __float2bfloat16(acc[m][n][j]);
                else
                    Cf[(size_t)row * N + col] = acc[m][n][j];
            }
        }
    }
}

// ---------------------------------------------------------------------------
// Flash attention (causal), swapped-QK^T, block-shared double-buffered K/V
// LDS staging, triangle-paired q-tiles for uniform block duration.
// Block = 4 waves x 32 q-rows = 128 q; passes qt = 15-y then y (34 tile-iters
// total for every block). Per 64-key tile: stage(next) via global_load_lds
// (pre-swizzled source, linear LDS dest), QK^T = 16 MFMA from LDS K,
// in-register softmax (stats at lane l15=q, 2 shfl_xor), P via per-wave
// swizzled LDS buffer, PV = 16 MFMA from LDS V.
// ---------------------------------------------------------------------------
__global__ __launch_bounds__(256) void attn_k(const __hip_bfloat16* __restrict__ qkv,
                                              const __hip_bfloat16* __restrict__ Vt,
                                              __hip_bfloat16* __restrict__ y) {
    constexpr int TT = 2048;
    constexpr int S3C = 3072;
    const int bh = blockIdx.x, b = bh >> 4, h = bh & 15;
    const int tid = threadIdx.x;
    const int wid = tid >> 6, lane = tid & 63;
    const int l15 = lane & 15, lg = lane >> 4;

    __shared__ __attribute__((aligned(16))) char Ks[2][64 * 128];  // [key][d-chunk^swz]
    __shared__ __attribute__((aligned(16))) char Vs[2][64 * 128];  // [d][t-chunk^swz]
    __shared__ __attribute__((aligned(16))) char Pl[4][32 * 128];  // per-wave P
    char* P = &Pl[wid][0];

    const __hip_bfloat16* base = qkv + (size_t)b * TT * S3C;
    const int qo = h * 64, ko = 1024 + h * 64;
    const __hip_bfloat16* vt = Vt + (size_t)bh * 64 * TT;
    const float scale = 0.03125f;  // 1/sqrt(1024)

    // staging geometry: thread handles 16B slots tid and tid+256 of each tile;
    // slot s -> row s>>3, chunk s&7; source chunk pre-swizzled: c ^ (row&7).
    const int r0 = tid >> 3, r1 = r0 + 32, cc = tid & 7;
    const int col0 = 8 * (cc ^ (r0 & 7)), col1 = 8 * (cc ^ (r1 & 7));

#define STAGE(BUF, KT)                                                                            \
    do {                                                                                          \
        const int kb_ = (KT) * 64;                                                                \
        __builtin_amdgcn_global_load_lds(                                                         \
            (const __attribute__((address_space(1))) void*)(base + (size_t)(kb_ + r0) * S3C + ko + col0), \
            (__attribute__((address_space(3))) void*)(&Ks[BUF][tid * 16]), 16, 0, 0);             \
        __builtin_amdgcn_global_load_lds(                                                         \
            (const __attribute__((address_space(1))) void*)(base + (size_t)(kb_ + r1) * S3C + ko + col1), \
            (__attribute__((address_space(3))) void*)(&Ks[BUF][tid * 16 + 4096]), 16, 0, 0);      \
        __builtin_amdgcn_global_load_lds(                                                         \
            (const __attribute__((address_space(1))) void*)(vt + (size_t)r0 * TT + kb_ + col0),   \
            (__attribute__((address_space(3))) void*)(&Vs[BUF][tid * 16]), 16, 0, 0);             \
        __builtin_amdgcn_global_load_lds(                                                         \
            (const __attribute__((address_space(1))) void*)(vt + (size_t)r1 * TT + kb_ + col1),   \
            (__attribute__((address_space(3))) void*)(&Vs[BUF][tid * 16 + 4096]), 16, 0, 0);      \
    } while (0)

#pragma unroll 1
    for (int pass = 0; pass < 2; ++pass) {
        const int qt = pass == 0 ? (15 - (int)blockIdx.y) : (int)blockIdx.y;
        const int qbase = qt * 128 + wid * 32;
        const int my_nt = (qbase >> 6) + 1;  // tiles this wave computes
        const int blk_nt = qt * 2 + 2;       // tiles the block stages

        // Q B-fragments: [m][half]: Q[q=qbase+m*16+l15][d=half*32+lg*8 ..]
        bf16x8 aq[2][2];
#pragma unroll
        for (int m = 0; m < 2; ++m) {
            const __hip_bfloat16* qp = base + (size_t)(qbase + m * 16 + l15) * S3C + qo + lg * 8;
            aq[m][0] = *reinterpret_cast<const bf16x8*>(qp);
            aq[m][1] = *reinterpret_cast<const bf16x8*>(qp + 32);
        }

        float mrow[2] = {-1e30f, -1e30f}, lrow[2] = {0.f, 0.f};
        f32x4 acc[2][4] = {};  // [m][dg]: row=q(lg*4+j), col=d(dg*16+l15)

        STAGE(0, 0);
        asm volatile("s_waitcnt vmcnt(0)" ::: "memory");
        __syncthreads();

        int cur = 0;
        for (int kt = 0; kt < blk_nt; ++kt) {
            if (kt + 1 < blk_nt) STAGE(cur ^ 1, kt + 1);
            if (kt < my_nt) {
                const int kb = kt * 64;
                const char* Kb = &Ks[cur][0];
                const char* Vb = &Vs[cur][0];
                const int sw = l15 & 7;
                // ---- QK^T (swapped): s[m][cg][j] = S[key=kb+16cg+4lg+j][q=qbase+16m+l15]
                f32x4 s[2][4];
#pragma unroll
                for (int cg = 0; cg < 4; ++cg) {
                    const char* krow = Kb + (cg * 16 + l15) * 128;
                    bf16x8 k0 = *reinterpret_cast<const bf16x8*>(krow + 16 * (lg ^ sw));
                    bf16x8 k1 = *reinterpret_cast<const bf16x8*>(krow + 16 * ((4 + lg) ^ sw));
#pragma unroll
                    for (int m = 0; m < 2; ++m) {
                        f32x4 z = {0.f, 0.f, 0.f, 0.f};
                        z = __builtin_amdgcn_mfma_f32_16x16x32_bf16(k0, aq[m][0], z, 0, 0, 0);
                        z = __builtin_amdgcn_mfma_f32_16x16x32_bf16(k1, aq[m][1], z, 0, 0, 0);
                        s[m][cg] = z;
                    }
                }
                // ---- scale + causal mask
                float p[2][4][4];
                const bool needmask = (kb + 63 > qbase);
#pragma unroll
                for (int m = 0; m < 2; ++m)
#pragma unroll
                    for (int cg = 0; cg < 4; ++cg)
#pragma unroll
                        for (int j = 0; j < 4; ++j) {
                            float v = s[m][cg][j] * scale;
                            if (needmask) {
                                int key = kb + cg * 16 + lg * 4 + j;
                                int qrow = qbase + m * 16 + l15;
                                v = (key > qrow) ? -1e30f : v;
                            }
                            p[m][cg][j] = v;
                        }
                // ---- online softmax (stats at lane l15 = q)
                float rs[2];
#pragma unroll
                for (int m = 0; m < 2; ++m) {
                    float c0_ = fmaxf(fmaxf(p[m][0][0], p[m][0][1]), fmaxf(p[m][0][2], p[m][0][3]));
                    float c1_ = fmaxf(fmaxf(p[m][1][0], p[m][1][1]), fmaxf(p[m][1][2], p[m][1][3]));
                    float c2_ = fmaxf(fmaxf(p[m][2][0], p[m][2][1]), fmaxf(p[m][2][2], p[m][2][3]));
                    float c3_ = fmaxf(fmaxf(p[m][3][0], p[m][3][1]), fmaxf(p[m][3][2], p[m][3][3]));
                    float tm = fmaxf(fmaxf(c0_, c1_), fmaxf(c2_, c3_));
                    tm = fmaxf(tm, __shfl_xor(tm, 16, 64));
                    tm = fmaxf(tm, __shfl_xor(tm, 32, 64));
                    float mn = fmaxf(mrow[m], tm);
                    rs[m] = __expf(mrow[m] - mn);
                    float ssum = 0.f;
#pragma unroll
                    for (int cg = 0; cg < 4; ++cg) {
                        float e0 = __expf(p[m][cg][0] - mn);
                        float e1 = __expf(p[m][cg][1] - mn);
                        float e2 = __expf(p[m][cg][2] - mn);
                        float e3 = __expf(p[m][cg][3] - mn);
                        p[m][cg][0] = e0; p[m][cg][1] = e1; p[m][cg][2] = e2; p[m][cg][3] = e3;
                        ssum += (e0 + e1) + (e2 + e3);
                    }
                    ssum += __shfl_xor(ssum, 16, 64);
                    ssum += __shfl_xor(ssum, 32, 64);
                    lrow[m] = lrow[m] * rs[m] + ssum;
                    mrow[m] = mn;
                }
                // ---- rescale acc
#pragma unroll
                for (int m = 0; m < 2; ++m)
#pragma unroll
                    for (int j = 0; j < 4; ++j) {
                        float r4 = __shfl(rs[m], lg * 4 + j, 64);
#pragma unroll
                        for (int dg = 0; dg < 4; ++dg)
                            acc[m][dg][j] *= r4;
                    }
                // ---- V B-frags from LDS (issued before P round-trip wait)
                bf16x8 vb[2][4];
#pragma unroll
                for (int dg = 0; dg < 4; ++dg) {
                    const char* vrow = Vb + (dg * 16 + l15) * 128;
                    vb[0][dg] = *reinterpret_cast<const bf16x8*>(vrow + 16 * (lg ^ sw));
                    vb[1][dg] = *reinterpret_cast<const bf16x8*>(vrow + 16 * ((4 + lg) ^ sw));
                }
                // ---- P -> LDS (packed b64, swizzled)
#pragma unroll
                for (int m = 0; m < 2; ++m) {
                    const int ql = m * 16 + l15;
                    const int swz = (ql & 7) << 3;
#pragma unroll
                    for (int cg = 0; cg < 4; ++cg) {
                        __hip_bfloat16 h0 = __float2bfloat16(p[m][cg][0]);
                        __hip_bfloat16 h1 = __float2bfloat16(p[m][cg][1]);
                        __hip_bfloat16 h2 = __float2bfloat16(p[m][cg][2]);
                        __hip_bfloat16 h3 = __float2bfloat16(p[m][cg][3]);
                        uint2 u;
                        u.x = (unsigned)*(unsigned short*)&h0 | ((unsigned)*(unsigned short*)&h1 << 16);
                        u.y = (unsigned)*(unsigned short*)&h2 | ((unsigned)*(unsigned short*)&h3 << 16);
                        int keyx = (cg * 16 + lg * 4) ^ swz;
                        *reinterpret_cast<uint2*>(P + ql * 128 + keyx * 2) = u;
                    }
                }
                asm volatile("s_waitcnt lgkmcnt(0)" ::: "memory");
                __builtin_amdgcn_sched_barrier(0);
                // ---- P A-frags + PV
                bf16x8 pa[2][2];
#pragma unroll
                for (int m = 0; m < 2; ++m) {
                    const int ql = m * 16 + l15;
                    const int swz = (ql & 7) << 3;
#pragma unroll
                    for (int ks = 0; ks < 2; ++ks) {
                        int keyx = (ks * 32 + lg * 8) ^ swz;
                        pa[m][ks] = *reinterpret_cast<const bf16x8*>(P + ql * 128 + keyx * 2);
                    }
                }
                asm volatile("s_waitcnt lgkmcnt(0)" ::: "memory");
                __builtin_amdgcn_sched_barrier(0);
#pragma unroll
                for (int ks = 0; ks < 2; ++ks)
#pragma unroll
                    for (int dg = 0; dg < 4; ++dg)
#pragma unroll
                        for (int m = 0; m < 2; ++m)
                            acc[m][dg] = __builtin_amdgcn_mfma_f32_16x16x32_bf16(
                                pa[m][ks], vb[ks][dg], acc[m][dg], 0, 0, 0);
            }
            asm volatile("s_waitcnt vmcnt(0)" ::: "memory");
            __syncthreads();
            cur ^= 1;
        }

        // ---- epilogue: redistribute lrow, divide, store
#pragma unroll
        for (int m = 0; m < 2; ++m)
#pragma unroll
            for (int j = 0; j < 4; ++j) {
                float lr = __shfl(lrow[m], lg * 4 + j, 64);
                float inv = 1.f / lr;
                int t = qbase + m * 16 + lg * 4 + j;
#pragma unroll
                for (int dg = 0; dg < 4; ++dg) {
                    float o = acc[m][dg][j] * inv;
                    y[((size_t)(b * TT + t)) * 1024 + h * 64 + dg * 16 + l15] = __float2bfloat16(o);
                }
            }
        __syncthreads();  // pass isolation before re-staging buf 0
    }
#undef STAGE
}

// ---------------------------------------------------------------------------
extern "C" void kernel_launch(void* const* d_in, const int* in_sizes, int n_in,
                              void* d_out, int out_size, void* d_ws, size_t ws_size,
                              hipStream_t stream) {
    const float* x = (const float*)d_in[0];   // [4,2048,1024]
    const float* Wa = (const float*)d_in[1];  // [1024,3072]
    const float* Wp = (const float*)d_in[2];  // [1024,1024]
    float* out = (float*)d_out;               // [4,2048,1024] fp32

    __hip_bfloat16* ws = (__hip_bfloat16*)d_ws;
    __hip_bfloat16* x_bf = ws;                          // 8192*1024 (dead after GEMM1)
    __hip_bfloat16* WaT = x_bf + (size_t)8192 * 1024;   // 3072*1024 (W_attn^T)
    __hip_bfloat16* WpT = WaT + (size_t)3072 * 1024;    // 1024*1024 (W_proj^T)
    __hip_bfloat16* qkv = WpT + (size_t)1024 * 1024;    // 8192*3072
    __hip_bfloat16* ybf = qkv + (size_t)8192 * 3072;    // 8192*1024
    __hip_bfloat16* Vt = x_bf;                          // reuse: 64*64*2048 = 8192*1024

    cvt_f32_to_bf16_k<<<8192, 256, 0, stream>>>(x, x_bf, 2097152);
    transpose_cvt<<<dim3(96, 32), 256, 0, stream>>>(Wa, WaT, 1024, 3072);
    transpose_cvt<<<dim3(32, 32), 256, 0, stream>>>(Wp, WpT, 1024, 1024);
    // qkv = x @ W_attn   (M=8192, N=3072, K=1024)
    gemm_bt<true><<<dim3(24, 64), 256, 0, stream>>>(x_bf, WaT, qkv, nullptr, 8192, 3072, 1024);
    // V^T per head (x_bf is dead now; Vt aliases it)
    vtrans_k<<<dim3(64, 2, 64), 256, 0, stream>>>(qkv, Vt);
    // flash attention -> ybf (triangle-paired q-tiles)
    attn_k<<<dim3(64, 8), 256, 0, stream>>>(qkv, Vt, ybf);
    // out = y @ W_proj   (M=8192, N=1024, K=1024), fp32 out
    gemm_bt<false><<<dim3(8, 64), 256, 0, stream>>>(ybf, WpT, nullptr, out, 8192, 1024, 1024);
}